// Round 15
// baseline (222.531 us; speedup 1.0000x reference)
//
#include <hip/hip_runtime.h>

// SimpleSNN: T=16, B=4096, N_IN=784, N_HID=256, N_OUT=10
//   conv_x      : X fp32 {0,1} -> Xq4T nibbles, TILED [t][b/16][kt][r][32B]
//   conv_w3     : W1 -> 3 i8 planes, w = 2^-11 a + 2^-18 b + 2^-25 c
//   gemm1_lif1  : FUSED. 256 blocks = 64 m-tiles(64r) x 4 n-slices(64c);
//                 4 waves of 16m x 64n; W-LDS 159,744 B (XOR k-slot swizzle,
//                 conflict-free b128); 1 wave/SIMD, t-tiled x4 -> 48 indep
//                 MFMA/k-step (pure ILP); A 3-deep rolling prefetch; spikes
//                 stored as ONE 256B tile per wave-instruction (Z1S layout).
//   gemm2_f32   : C2T[o][m] from Z1S tiles (same summation expr as r13)
//   lif2        : reads C2T

#define T_STEPS 16
#define B_SZ    4096
#define N_IN    784
#define N_HID   256
#define N_OUT   10
#define M_TOT   (T_STEPS * B_SZ)   // 65536
#define KP8     832                // 13 * 64
#define NKT     13                 // K=64 steps
#define WPLANE  (N_HID * KP8)      // i8 elems per W plane (global)
#define PL      (64 * 832)         // per-plane LDS bytes (53,248)
#define TSH     ((size_t)256 * NKT * 512)   // Xq4T per-t stride

typedef int    i32x4 __attribute__((ext_vector_type(4)));
typedef unsigned int u32;
typedef unsigned char u8;

#if defined(__has_builtin) && __has_builtin(__builtin_amdgcn_perm)
__device__ __forceinline__ u32 ilv(u32 hi, u32 lo) {
    return __builtin_amdgcn_perm(hi, lo, 0x05010400u);
}
__device__ __forceinline__ u32 ilv_hi(u32 hi, u32 lo) {
    return __builtin_amdgcn_perm(hi, lo, 0x07030602u);
}
#else
__device__ __forceinline__ u32 ilv(u32 hi, u32 lo) {
    return (lo & 0xFFu) | ((hi & 0xFFu) << 8) |
           ((lo & 0xFF00u) << 8) | ((hi & 0xFF00u) << 16);
}
__device__ __forceinline__ u32 ilv_hi(u32 hi, u32 lo) { return ilv(hi >> 16, lo >> 16); }
#endif

__device__ __forceinline__ uint4 unp(uint2 u) {   // 8 nibble-bytes -> 16 i8 {0,1}
    const u32 lo0 = u.x & 0x0F0F0F0Fu, hi0 = (u.x >> 4) & 0x0F0F0F0Fu;
    const u32 lo1 = u.y & 0x0F0F0F0Fu, hi1 = (u.y >> 4) & 0x0F0F0F0Fu;
    uint4 r;
    r.x = ilv(hi0, lo0);
    r.y = ilv_hi(hi0, lo0);
    r.z = ilv(hi1, lo1);
    r.w = ilv_hi(hi1, lo1);
    return r;
}

// ---------------- conv_x: fp32 {0,1} -> Xq4T tiled nibbles [r13-verified] ---
__global__ __launch_bounds__(256) void conv_x(
    const float* __restrict__ X, u8* __restrict__ Xq4T)
{
    const int idx = blockIdx.x * 256 + threadIdx.x;   // uint2 units
    const int q  = idx & 63;
    const int h  = idx >> 6;
    const int kt = h % NKT;
    const int u  = h / NKT;
    const int bg = u & 255;
    const int t  = u >> 8;
    const int r  = q >> 2;
    const int ls = q & 3;
    const long m  = (long)t * B_SZ + bg * 16 + r;
    const int k0 = kt * 64 + ls * 16;
    uint2 o = make_uint2(0u, 0u);
    if (k0 + 16 <= N_IN) {
        const uint4* src = reinterpret_cast<const uint4*>(X + m * N_IN + k0);
        const uint4 f0 = src[0], f1 = src[1], f2 = src[2], f3 = src[3];
        auto nib = [](uint4 a, uint4 b) -> u32 {
            return (a.x ? 1u : 0u)        | ((a.y ? 1u : 0u) << 4)  |
                   ((a.z ? 1u : 0u) << 8) | ((a.w ? 1u : 0u) << 12) |
                   ((b.x ? 1u : 0u) << 16)| ((b.y ? 1u : 0u) << 20) |
                   ((b.z ? 1u : 0u) << 24)| ((b.w ? 1u : 0u) << 28);
        };
        o.x = nib(f0, f1);
        o.y = nib(f2, f3);
    }
    reinterpret_cast<uint2*>(Xq4T)[idx] = o;
}

// ---------------- conv_w3: W1 -> 3 i8 planes (power-of-2 scales) -----------
__global__ __launch_bounds__(256) void conv_w3(
    const float* __restrict__ W1, char* __restrict__ Wq)
{
    const int idx = blockIdx.x * 256 + threadIdx.x;   // over 256*832
    if (idx >= N_HID * KP8) return;
    const int n = idx / KP8, k = idx % KP8;
    const float w = (k < N_IN) ? W1[n * N_IN + k] : 0.0f;
    const float a = rintf(w * 2048.0f);                       // s1 = 2^-11
    const float r1 = fmaf(a, -4.8828125e-4f, w);
    const float b = rintf(r1 * 262144.0f);                    // s2 = 2^-18
    const float r2 = fmaf(b, -3.814697265625e-6f, r1);
    const float c = rintf(r2 * 33554432.0f);                  // s3 = 2^-25
    Wq[idx]              = (char)(int)a;
    Wq[WPLANE + idx]     = (char)(int)b;
    Wq[2 * WPLANE + idx] = (char)(int)c;
}

// ---------------- gemm1 + lif1 fused ---------------------------------------
__global__ __launch_bounds__(256, 1) void gemm1_lif1(
    const u8* __restrict__ Xq4T,
    const u8* __restrict__ Wq,
    const float* __restrict__ b1,
    u8* __restrict__ Z1S)
{
    // per-plane LDS [64 cols][52 slots of 16B]; phys slot sp holds logical
    // slot sp^(c&7) for sp<48 (slots 48..51 unswizzled tail)
    __shared__ u8 Bq[3 * PL];           // 159,744 B

    const int tid  = threadIdx.x;
    const int lane = tid & 63;
    const int w    = tid >> 6;          // wave 0..3: m-rows w*16..+16
    const int bid  = blockIdx.x;        // 256 blocks
    const int l    = (bid & 7) * 32 + (bid >> 3);   // XCD-grouped
    const int mt   = l >> 2;            // m-tile of 64 rows (0..63)
    const int ns   = l & 3;             // n-slice of 64 cols
    const int n0   = ns * 64;
    const int ls   = lane >> 4;         // k-slot 0..3
    const int lr   = lane & 15;

    // ---- stage W -> LDS (source k-slot swizzled; dest linear) ----
    #pragma unroll
    for (int it = 0; it < 39; ++it) {   // 3*64*52 = 9984 units / 256 thr
        const int u  = it * 256 + tid;
        const int p  = u / 3328;
        const int rm = u - p * 3328;
        const int c  = rm / 52;
        const int sp = rm - c * 52;
        const int ss = (sp < 48) ? (sp ^ (c & 7)) : sp;
        const uint4 v = *reinterpret_cast<const uint4*>(
            Wq + (size_t)p * WPLANE + (size_t)(n0 + c) * KP8 + ss * 16);
        *reinterpret_cast<uint4*>(&Bq[p * PL + c * 832 + sp * 16]) = v;
    }
    __syncthreads();                    // the only barrier

    float bbv[4];
    #pragma unroll
    for (int cf = 0; cf < 4; ++cf) bbv[cf] = b1[n0 + cf * 16 + lr];
    float vS[16], cS[16];               // LIF state per (cf,q)
    #pragma unroll
    for (int k = 0; k < 16; ++k) { vS[k] = 0.0f; cS[k] = 0.0f; }

    const int x_hi = (lr >> 2) & 1;     // swizzle bits of c&7 (c = cf*16+lr)
    const int x_lo = lr & 3;
    int rb[4][3];                       // read base per (cf, plane), kt<12
    #pragma unroll
    for (int cf = 0; cf < 4; ++cf)
        #pragma unroll
        for (int p = 0; p < 3; ++p)
            rb[cf][p] = p * PL + (cf * 16 + lr) * 832 + ((ls ^ x_lo) << 4);

    const int bg = mt * 4 + w;          // this wave's 16-row group
    const u8* aP = Xq4T + (size_t)bg * (NKT * 512) + lr * 32 + ls * 8;

    const float s1 = 4.8828125e-4f;          // 2^-11
    const float s2 = 3.814697265625e-6f;     // 2^-18
    const float s3 = 2.9802322387695312e-8f; // 2^-25

    for (int g = 0; g < 4; ++g) {       // 4 groups x 4 timesteps
        i32x4 acc[4][4][3];             // [tt][cf][plane]
        #pragma unroll
        for (int tt = 0; tt < 4; ++tt)
            #pragma unroll
            for (int cf = 0; cf < 4; ++cf)
                #pragma unroll
                for (int p = 0; p < 3; ++p)
                    acc[tt][cf][p] = (i32x4){0, 0, 0, 0};

        uint2 ar[4][4];                 // rolling A [slot][tt], 3-deep prefetch
        #pragma unroll
        for (int pk = 0; pk < 3; ++pk)
            #pragma unroll
            for (int tt = 0; tt < 4; ++tt)
                ar[pk][tt] = *reinterpret_cast<const uint2*>(
                    aP + tt * TSH + pk * 512);

        #pragma unroll
        for (int kt = 0; kt < NKT; ++kt) {
            if (kt + 3 < NKT) {         // prefetch 3 k-steps ahead
                #pragma unroll
                for (int tt = 0; tt < 4; ++tt)
                    ar[(kt + 3) & 3][tt] = *reinterpret_cast<const uint2*>(
                        aP + tt * TSH + (kt + 3) * 512);
            }
            uint4 bf[4][3];
            if (kt < 12) {
                const int k6 = (kt ^ x_hi) << 6;
                #pragma unroll
                for (int cf = 0; cf < 4; ++cf)
                    #pragma unroll
                    for (int p = 0; p < 3; ++p)
                        bf[cf][p] = *reinterpret_cast<const uint4*>(
                            &Bq[rb[cf][p] + k6]);
            } else {                    // tail slots 48..51, unswizzled
                #pragma unroll
                for (int cf = 0; cf < 4; ++cf)
                    #pragma unroll
                    for (int p = 0; p < 3; ++p)
                        bf[cf][p] = *reinterpret_cast<const uint4*>(
                            &Bq[p * PL + (cf * 16 + lr) * 832 + 768 + (ls << 4)]);
            }
            uint4 af[4];
            #pragma unroll
            for (int tt = 0; tt < 4; ++tt)
                af[tt] = unp(ar[kt & 3][tt]);

            #pragma unroll
            for (int tt = 0; tt < 4; ++tt)
                #pragma unroll
                for (int cf = 0; cf < 4; ++cf)
                    #pragma unroll
                    for (int p = 0; p < 3; ++p)
                        acc[tt][cf][p] = __builtin_amdgcn_mfma_i32_16x16x64_i8(
                            __builtin_bit_cast(i32x4, af[tt]),
                            __builtin_bit_cast(i32x4, bf[cf][p]),
                            acc[tt][cf][p], 0, 0, 0);
        }
        aP += 4 * TSH;

        // LIF + store: per (tt,cf) one 256B tile per wave, single u32 store
        #pragma unroll
        for (int tt = 0; tt < 4; ++tt) {
            const int t = 4 * g + tt;
            #pragma unroll
            for (int cf = 0; cf < 4; ++cf) {
                u32 zw = 0;
                #pragma unroll
                for (int q = 0; q < 4; ++q) {
                    const int k = cf * 4 + q;
                    const float c1 = fmaf(s1, (float)acc[tt][cf][0][q],
                                     fmaf(s2, (float)acc[tt][cf][1][q],
                                     fmaf(s3, (float)acc[tt][cf][2][q], bbv[cf])));
                    const float vd = vS[k] + 0.1f * ((0.0f - vS[k]) + cS[k]);
                    const float id = cS[k] - 0.2f * cS[k];
                    const bool  sp = vd > 1.0f;
                    zw |= (sp ? 1u : 0u) << (8 * q);
                    vS[k] = sp ? 0.0f : vd;
                    cS[k] = id + c1;
                }
                const int nt = ns * 4 + cf;            // n-tile 0..15
                const int mts = mt * 4 + w;            // m-tile 0..255
                u32* dst = reinterpret_cast<u32*>(
                    Z1S + ((size_t)(t * 16 + nt) * 256 + mts) * 256
                        + lr * 16 + ls * 4);
                *dst = zw;
            }
        }
    }
}

// ---------------- GEMM2: C2T[o][m] from Z1S tiles --------------------------
__global__ __launch_bounds__(256) void gemm2_f32(
    const u8* __restrict__ Z1S, const float* __restrict__ W2,
    const float* __restrict__ b2, float* __restrict__ C2T)
{
    __shared__ float ws[N_OUT * N_HID];   // 10 KB
    const int tid = threadIdx.x;
    const int t   = blockIdx.x >> 4;
    const int b   = (blockIdx.x & 15) * 256 + tid;

    for (int i = tid; i < N_OUT * N_HID; i += 256) ws[i] = W2[i];
    __syncthreads();

    float acc[N_OUT];
    #pragma unroll
    for (int o = 0; o < N_OUT; ++o) acc[o] = b2[o];

    const u8* zb = Z1S + (size_t)(t * 16) * 65536
                 + (size_t)(b >> 4) * 256 + (b & 15);
    for (int n0 = 0; n0 < N_HID; n0 += 8) {        // nt fixed per group (8|16)
        const int nt = n0 >> 4, r0 = n0 & 15;
        const u8* zr = zb + (size_t)nt * 65536 + r0 * 16;
        float zf[8];
        #pragma unroll
        for (int j = 0; j < 8; ++j)
            zf[j] = (float)zr[j * 16];
        #pragma unroll
        for (int o = 0; o < N_OUT; ++o) {          // same expr as r13 (passed)
            acc[o] += zf[0] * ws[o * N_HID + n0 + 0] + zf[1] * ws[o * N_HID + n0 + 1]
                    + zf[2] * ws[o * N_HID + n0 + 2] + zf[3] * ws[o * N_HID + n0 + 3];
            acc[o] += zf[4] * ws[o * N_HID + n0 + 4] + zf[5] * ws[o * N_HID + n0 + 5]
                    + zf[6] * ws[o * N_HID + n0 + 6] + zf[7] * ws[o * N_HID + n0 + 7];
        }
    }
    #pragma unroll
    for (int o = 0; o < N_OUT; ++o)
        C2T[(size_t)o * M_TOT + t * B_SZ + b] = acc[o];
}

// ---------------- LIF2: thread = (o,b); reads C2T [r13-verified] -----------
__global__ __launch_bounds__(256) void lif2_kernel(
    const float* __restrict__ C2T, float* __restrict__ out)
{
    const int g = blockIdx.x * 256 + threadIdx.x;   // < 40960
    const int o = g >> 12;              // 0..9
    const int b = g & (B_SZ - 1);
    float v = 0.0f, cur = 0.0f, s = 0.0f;
    #pragma unroll
    for (int t = 0; t < T_STEPS; ++t) {
        const float c = C2T[(size_t)o * M_TOT + t * B_SZ + b];
        const float vd = v + 0.1f * ((0.0f - v) + cur);
        const float id = cur - 0.2f * cur;
        const bool  sp = vd > 1.0f;
        s += sp ? 1.0f : 0.0f;
        v = sp ? 0.0f : vd;
        cur = id + c;
    }
    out[b * N_OUT + o] = s;
}

extern "C" void kernel_launch(void* const* d_in, const int* in_sizes, int n_in,
                              void* d_out, int out_size, void* d_ws, size_t ws_size,
                              hipStream_t stream)
{
    const float* X  = (const float*)d_in[0];
    const float* W1 = (const float*)d_in[1];
    const float* b1 = (const float*)d_in[2];
    const float* W2 = (const float*)d_in[3];
    const float* b2 = (const float*)d_in[4];
    float* out = (float*)d_out;

    // ws: [Wq 0.64MB | pad->1MB][Xq4T 27.3MB][Z1S 16.8MB][C2T 2.6MB] ~48MB
    char* Wq = (char*)d_ws;
    u8*   Xq4T = (u8*)d_ws + (1 << 20);
    u8*   Z1S = Xq4T + (size_t)M_TOT * (KP8 / 2);
    float* C2T = (float*)(Z1S + (size_t)M_TOT * N_HID);

    conv_x<<<(M_TOT * 52) / 256, 256, 0, stream>>>(X, Xq4T);

    conv_w3<<<(N_HID * KP8 + 255) / 256, 256, 0, stream>>>(W1, Wq);

    gemm1_lif1<<<256, 256, 0, stream>>>(Xq4T, (const u8*)Wq, b1, Z1S);

    gemm2_f32<<<256, 256, 0, stream>>>(Z1S, W2, b2, C2T);

    lif2_kernel<<<(B_SZ * N_OUT) / 256, 256, 0, stream>>>(C2T, out);
}

// Round 16
// 172.431 us; speedup vs baseline: 1.2906x; 1.2906x over previous
//
#include <hip/hip_runtime.h>

// SimpleSNN: T=16, B=4096, N_IN=784, N_HID=256, N_OUT=10
//   conv_x      : X fp32 {0,1} -> Xq4T nibbles, TILED [t][b/16][kt][r][32B]
//   conv_w3     : W1 -> 3 i8 planes, w = 2^-11 a + 2^-18 b + 2^-25 c
//   gemm1_lif1  : FUSED. Wave tile 16m x 16n x t4 (acc 48 regs -> NO spill,
//                 cap 170 via __launch_bounds__(256,3)). 1024 blocks of 4
//                 waves (64m x 16n); W in LDS once (40,704B, 848-stride =
//                 uniform banks); 3 ds_read_b128 + 4 A-loads + 12 MFMA per
//                 k-step (B reg-reused across 4 t => LDS wall ~12.5us/CU);
//                 TLP 12 waves/CU hides A latency; Z1S 256B tile stores.
//   gemm2_f32   : C2T[o][m] from Z1S tiles [r15-verified]
//   lif2        : reads C2T [r13-verified]

#define T_STEPS 16
#define B_SZ    4096
#define N_IN    784
#define N_HID   256
#define N_OUT   10
#define M_TOT   (T_STEPS * B_SZ)   // 65536
#define KP8     832                // 13 * 64
#define NKT     13                 // K=64 steps
#define WPLANE  (N_HID * KP8)      // i8 elems per W plane (global)
#define WROW    848                // padded LDS row stride: uniform banks
#define WPL     (16 * WROW)        // per-plane LDS bytes (13568)
#define TSH     ((size_t)256 * NKT * 512)   // Xq4T per-t stride

typedef int    i32x4 __attribute__((ext_vector_type(4)));
typedef unsigned int u32;
typedef unsigned char u8;

#if defined(__has_builtin) && __has_builtin(__builtin_amdgcn_perm)
__device__ __forceinline__ u32 ilv(u32 hi, u32 lo) {
    return __builtin_amdgcn_perm(hi, lo, 0x05010400u);
}
__device__ __forceinline__ u32 ilv_hi(u32 hi, u32 lo) {
    return __builtin_amdgcn_perm(hi, lo, 0x07030602u);
}
#else
__device__ __forceinline__ u32 ilv(u32 hi, u32 lo) {
    return (lo & 0xFFu) | ((hi & 0xFFu) << 8) |
           ((lo & 0xFF00u) << 8) | ((hi & 0xFF00u) << 16);
}
__device__ __forceinline__ u32 ilv_hi(u32 hi, u32 lo) { return ilv(hi >> 16, lo >> 16); }
#endif

__device__ __forceinline__ uint4 unp(uint2 u) {   // 8 nibble-bytes -> 16 i8 {0,1}
    const u32 lo0 = u.x & 0x0F0F0F0Fu, hi0 = (u.x >> 4) & 0x0F0F0F0Fu;
    const u32 lo1 = u.y & 0x0F0F0F0Fu, hi1 = (u.y >> 4) & 0x0F0F0F0Fu;
    uint4 r;
    r.x = ilv(hi0, lo0);
    r.y = ilv_hi(hi0, lo0);
    r.z = ilv(hi1, lo1);
    r.w = ilv_hi(hi1, lo1);
    return r;
}

// ---------------- conv_x: fp32 {0,1} -> Xq4T tiled nibbles [r13-verified] ---
__global__ __launch_bounds__(256) void conv_x(
    const float* __restrict__ X, u8* __restrict__ Xq4T)
{
    const int idx = blockIdx.x * 256 + threadIdx.x;   // uint2 units
    const int q  = idx & 63;
    const int h  = idx >> 6;
    const int kt = h % NKT;
    const int u  = h / NKT;
    const int bg = u & 255;
    const int t  = u >> 8;
    const int r  = q >> 2;
    const int ls = q & 3;
    const long m  = (long)t * B_SZ + bg * 16 + r;
    const int k0 = kt * 64 + ls * 16;
    uint2 o = make_uint2(0u, 0u);
    if (k0 + 16 <= N_IN) {
        const uint4* src = reinterpret_cast<const uint4*>(X + m * N_IN + k0);
        const uint4 f0 = src[0], f1 = src[1], f2 = src[2], f3 = src[3];
        auto nib = [](uint4 a, uint4 b) -> u32 {
            return (a.x ? 1u : 0u)        | ((a.y ? 1u : 0u) << 4)  |
                   ((a.z ? 1u : 0u) << 8) | ((a.w ? 1u : 0u) << 12) |
                   ((b.x ? 1u : 0u) << 16)| ((b.y ? 1u : 0u) << 20) |
                   ((b.z ? 1u : 0u) << 24)| ((b.w ? 1u : 0u) << 28);
        };
        o.x = nib(f0, f1);
        o.y = nib(f2, f3);
    }
    reinterpret_cast<uint2*>(Xq4T)[idx] = o;
}

// ---------------- conv_w3: W1 -> 3 i8 planes (power-of-2 scales) -----------
__global__ __launch_bounds__(256) void conv_w3(
    const float* __restrict__ W1, char* __restrict__ Wq)
{
    const int idx = blockIdx.x * 256 + threadIdx.x;   // over 256*832
    if (idx >= N_HID * KP8) return;
    const int n = idx / KP8, k = idx % KP8;
    const float w = (k < N_IN) ? W1[n * N_IN + k] : 0.0f;
    const float a = rintf(w * 2048.0f);                       // s1 = 2^-11
    const float r1 = fmaf(a, -4.8828125e-4f, w);
    const float b = rintf(r1 * 262144.0f);                    // s2 = 2^-18
    const float r2 = fmaf(b, -3.814697265625e-6f, r1);
    const float c = rintf(r2 * 33554432.0f);                  // s3 = 2^-25
    Wq[idx]              = (char)(int)a;
    Wq[WPLANE + idx]     = (char)(int)b;
    Wq[2 * WPLANE + idx] = (char)(int)c;
}

// ---------------- gemm1 + lif1 fused: 16x16xT4 waves, no spill -------------
__global__ __launch_bounds__(256, 3) void gemm1_lif1(
    const u8* __restrict__ Xq4T,
    const u8* __restrict__ Wq,
    const float* __restrict__ b1,
    u8* __restrict__ Z1S)
{
    __shared__ u8 Bq[3 * WPL];          // 40,704 B -> 3 blocks/CU (reg-capped)

    const int tid  = threadIdx.x;
    const int lane = tid & 63;
    const int w    = tid >> 6;          // wave 0..3: m-rows w*16..+16
    const int bid  = blockIdx.x;        // 1024 blocks
    const int l    = (bid & 7) * 128 + (bid >> 3);  // XCD-grouped
    const int bt   = l >> 4;            // b-tile of 64 rows (0..63)
    const int nt   = l & 15;            // n-tile of 16 cols (0..15)
    const int n0   = nt * 16;
    const int ls   = lane >> 4;         // k-slot 0..3
    const int lr   = lane & 15;

    // ---- W -> LDS via regs (r9-verified staging; 848 stride) ----
    #pragma unroll
    for (int it = 0; it < 10; ++it) {
        const int u = it * 256 + tid;                 // 3*16*52 = 2496 units
        if (u < 2496) {
            const int plane = u / 832;
            const int rem   = u - plane * 832;
            const int row   = rem / 52;               // col within slice
            const int sp    = rem - row * 52;         // 16B slot
            const uint4 v = *reinterpret_cast<const uint4*>(
                Wq + (size_t)plane * WPLANE + (size_t)(n0 + row) * KP8 + sp * 16);
            *reinterpret_cast<uint4*>(&Bq[plane * WPL + row * WROW + sp * 16]) = v;
        }
    }
    __syncthreads();                    // the only barrier

    const float bb = b1[n0 + lr];
    float vS[4], cS[4];                 // LIF state: m = bg*16 + ls*4+q
    #pragma unroll
    for (int k = 0; k < 4; ++k) { vS[k] = 0.0f; cS[k] = 0.0f; }

    int bO[3];
    #pragma unroll
    for (int p = 0; p < 3; ++p) bO[p] = p * WPL + lr * WROW + (ls << 4);

    const int bg = bt * 4 + w;          // this wave's 16-row group (0..255)
    const u8* aP = Xq4T + (size_t)bg * (NKT * 512) + lr * 32 + ls * 8;

    const float s1 = 4.8828125e-4f;          // 2^-11
    const float s2 = 3.814697265625e-6f;     // 2^-18
    const float s3 = 2.9802322387695312e-8f; // 2^-25

    for (int g = 0; g < 4; ++g) {       // 4 groups x 4 timesteps
        i32x4 acc[4][3];                // [tt][plane] = 48 regs
        #pragma unroll
        for (int tt = 0; tt < 4; ++tt)
            #pragma unroll
            for (int p = 0; p < 3; ++p)
                acc[tt][p] = (i32x4){0, 0, 0, 0};

        uint2 ar[3][4];                 // rolling A [ring][tt], 2-step lead
        #pragma unroll
        for (int pk = 0; pk < 2; ++pk)
            #pragma unroll
            for (int tt = 0; tt < 4; ++tt)
                ar[pk][tt] = *reinterpret_cast<const uint2*>(
                    aP + tt * TSH + pk * 512);

        #pragma unroll
        for (int kt = 0; kt < NKT; ++kt) {
            if (kt + 2 < NKT) {         // prefetch 2 k-steps ahead (static ring)
                #pragma unroll
                for (int tt = 0; tt < 4; ++tt)
                    ar[(kt + 2) % 3][tt] = *reinterpret_cast<const uint2*>(
                        aP + tt * TSH + (kt + 2) * 512);
            }
            uint4 bf[3];
            #pragma unroll
            for (int p = 0; p < 3; ++p)
                bf[p] = *reinterpret_cast<const uint4*>(&Bq[bO[p] + kt * 64]);

            __builtin_amdgcn_s_setprio(1);
            #pragma unroll
            for (int tt = 0; tt < 4; ++tt) {
                const uint4 af = unp(ar[kt % 3][tt]);
                #pragma unroll
                for (int p = 0; p < 3; ++p)
                    acc[tt][p] = __builtin_amdgcn_mfma_i32_16x16x64_i8(
                        __builtin_bit_cast(i32x4, af),
                        __builtin_bit_cast(i32x4, bf[p]),
                        acc[tt][p], 0, 0, 0);
            }
            __builtin_amdgcn_s_setprio(0);
        }
        aP += 4 * TSH;

        // LIF + store: per tt one 256B tile per wave (2 full exclusive lines)
        #pragma unroll
        for (int tt = 0; tt < 4; ++tt) {
            const int t = 4 * g + tt;
            u32 zw = 0;
            #pragma unroll
            for (int q = 0; q < 4; ++q) {
                const float c1 = fmaf(s1, (float)acc[tt][0][q],
                                 fmaf(s2, (float)acc[tt][1][q],
                                 fmaf(s3, (float)acc[tt][2][q], bb)));
                const float vd = vS[q] + 0.1f * ((0.0f - vS[q]) + cS[q]);
                const float id = cS[q] - 0.2f * cS[q];
                const bool  sp = vd > 1.0f;
                zw |= (sp ? 1u : 0u) << (8 * q);
                vS[q] = sp ? 0.0f : vd;
                cS[q] = id + c1;
            }
            u32* dst = reinterpret_cast<u32*>(
                Z1S + ((size_t)(t * 16 + nt) * 256 + bg) * 256
                    + lr * 16 + ls * 4);
            *dst = zw;
        }
    }
}

// ---------------- GEMM2: C2T[o][m] from Z1S tiles [r15-verified] -----------
__global__ __launch_bounds__(256) void gemm2_f32(
    const u8* __restrict__ Z1S, const float* __restrict__ W2,
    const float* __restrict__ b2, float* __restrict__ C2T)
{
    __shared__ float ws[N_OUT * N_HID];   // 10 KB
    const int tid = threadIdx.x;
    const int t   = blockIdx.x >> 4;
    const int b   = (blockIdx.x & 15) * 256 + tid;

    for (int i = tid; i < N_OUT * N_HID; i += 256) ws[i] = W2[i];
    __syncthreads();

    float acc[N_OUT];
    #pragma unroll
    for (int o = 0; o < N_OUT; ++o) acc[o] = b2[o];

    const u8* zb = Z1S + (size_t)(t * 16) * 65536
                 + (size_t)(b >> 4) * 256 + (b & 15);
    for (int n0 = 0; n0 < N_HID; n0 += 8) {        // nt fixed per group
        const int nt = n0 >> 4, r0 = n0 & 15;
        const u8* zr = zb + (size_t)nt * 65536 + r0 * 16;
        float zf[8];
        #pragma unroll
        for (int j = 0; j < 8; ++j)
            zf[j] = (float)zr[j * 16];
        #pragma unroll
        for (int o = 0; o < N_OUT; ++o) {          // same expr as r13 (passed)
            acc[o] += zf[0] * ws[o * N_HID + n0 + 0] + zf[1] * ws[o * N_HID + n0 + 1]
                    + zf[2] * ws[o * N_HID + n0 + 2] + zf[3] * ws[o * N_HID + n0 + 3];
            acc[o] += zf[4] * ws[o * N_HID + n0 + 4] + zf[5] * ws[o * N_HID + n0 + 5]
                    + zf[6] * ws[o * N_HID + n0 + 6] + zf[7] * ws[o * N_HID + n0 + 7];
        }
    }
    #pragma unroll
    for (int o = 0; o < N_OUT; ++o)
        C2T[(size_t)o * M_TOT + t * B_SZ + b] = acc[o];
}

// ---------------- LIF2: thread = (o,b); reads C2T [r13-verified] -----------
__global__ __launch_bounds__(256) void lif2_kernel(
    const float* __restrict__ C2T, float* __restrict__ out)
{
    const int g = blockIdx.x * 256 + threadIdx.x;   // < 40960
    const int o = g >> 12;              // 0..9
    const int b = g & (B_SZ - 1);
    float v = 0.0f, cur = 0.0f, s = 0.0f;
    #pragma unroll
    for (int t = 0; t < T_STEPS; ++t) {
        const float c = C2T[(size_t)o * M_TOT + t * B_SZ + b];
        const float vd = v + 0.1f * ((0.0f - v) + cur);
        const float id = cur - 0.2f * cur;
        const bool  sp = vd > 1.0f;
        s += sp ? 1.0f : 0.0f;
        v = sp ? 0.0f : vd;
        cur = id + c;
    }
    out[b * N_OUT + o] = s;
}

extern "C" void kernel_launch(void* const* d_in, const int* in_sizes, int n_in,
                              void* d_out, int out_size, void* d_ws, size_t ws_size,
                              hipStream_t stream)
{
    const float* X  = (const float*)d_in[0];
    const float* W1 = (const float*)d_in[1];
    const float* b1 = (const float*)d_in[2];
    const float* W2 = (const float*)d_in[3];
    const float* b2 = (const float*)d_in[4];
    float* out = (float*)d_out;

    // ws: [Wq 0.64MB | pad->1MB][Xq4T 27.3MB][Z1S 16.8MB][C2T 2.6MB] ~48MB
    char* Wq = (char*)d_ws;
    u8*   Xq4T = (u8*)d_ws + (1 << 20);
    u8*   Z1S = Xq4T + (size_t)M_TOT * (KP8 / 2);
    float* C2T = (float*)(Z1S + (size_t)M_TOT * N_HID);

    conv_x<<<(M_TOT * 52) / 256, 256, 0, stream>>>(X, Xq4T);

    conv_w3<<<(N_HID * KP8 + 255) / 256, 256, 0, stream>>>(W1, Wq);

    gemm1_lif1<<<1024, 256, 0, stream>>>(Xq4T, (const u8*)Wq, b1, Z1S);

    gemm2_f32<<<256, 256, 0, stream>>>(Z1S, W2, b2, C2T);

    lif2_kernel<<<(B_SZ * N_OUT) / 256, 256, 0, stream>>>(C2T, out);
}

// Round 17
// 169.171 us; speedup vs baseline: 1.3154x; 1.0193x over previous
//
#include <hip/hip_runtime.h>

// SimpleSNN: T=16, B=4096, N_IN=784, N_HID=256, N_OUT=10
//   conv_x      : X fp32 {0,1} -> Xq4T nibbles, TILED [t][b/16][kt][r][32B]
//   conv_w3     : W1 -> 3 i8 planes, w = 2^-11 a + 2^-18 b + 2^-25 c
//   gemm1_lif1  : FUSED. Wave tile 16m x 16n x t4 (acc 48 regs, no spill).
//                 1024 blocks of 4 waves; W in LDS once (40,704B); 3 ds_read
//                 + 4 A-loads + 12 MFMA per k-step; spikes stored as one
//                 256B tile per wave with LANE-CONTIGUOUS byte order
//                 (lane L -> byte L*4; tile layout [m>>2][n][m&3]) so the
//                 store coalesces to two full 128B lines (r16 had lr*16+ls*4
//                 -> 8x write amplification, the r13-r16 poison).
//   gemm2_f32   : C2T[o][m] from Z1S tiles (updated indexing, same fp expr)
//   lif2        : reads C2T [r13-verified]

#define T_STEPS 16
#define B_SZ    4096
#define N_IN    784
#define N_HID   256
#define N_OUT   10
#define M_TOT   (T_STEPS * B_SZ)   // 65536
#define KP8     832                // 13 * 64
#define NKT     13                 // K=64 steps
#define WPLANE  (N_HID * KP8)      // i8 elems per W plane (global)
#define WROW    848                // padded LDS row stride: uniform banks
#define WPL     (16 * WROW)        // per-plane LDS bytes (13568)
#define TSH     ((size_t)256 * NKT * 512)   // Xq4T per-t stride

typedef int    i32x4 __attribute__((ext_vector_type(4)));
typedef unsigned int u32;
typedef unsigned char u8;

#if defined(__has_builtin) && __has_builtin(__builtin_amdgcn_perm)
__device__ __forceinline__ u32 ilv(u32 hi, u32 lo) {
    return __builtin_amdgcn_perm(hi, lo, 0x05010400u);
}
__device__ __forceinline__ u32 ilv_hi(u32 hi, u32 lo) {
    return __builtin_amdgcn_perm(hi, lo, 0x07030602u);
}
#else
__device__ __forceinline__ u32 ilv(u32 hi, u32 lo) {
    return (lo & 0xFFu) | ((hi & 0xFFu) << 8) |
           ((lo & 0xFF00u) << 8) | ((hi & 0xFF00u) << 16);
}
__device__ __forceinline__ u32 ilv_hi(u32 hi, u32 lo) { return ilv(hi >> 16, lo >> 16); }
#endif

__device__ __forceinline__ uint4 unp(uint2 u) {   // 8 nibble-bytes -> 16 i8 {0,1}
    const u32 lo0 = u.x & 0x0F0F0F0Fu, hi0 = (u.x >> 4) & 0x0F0F0F0Fu;
    const u32 lo1 = u.y & 0x0F0F0F0Fu, hi1 = (u.y >> 4) & 0x0F0F0F0Fu;
    uint4 r;
    r.x = ilv(hi0, lo0);
    r.y = ilv_hi(hi0, lo0);
    r.z = ilv(hi1, lo1);
    r.w = ilv_hi(hi1, lo1);
    return r;
}

// ---------------- conv_x: fp32 {0,1} -> Xq4T tiled nibbles [r13-verified] ---
__global__ __launch_bounds__(256) void conv_x(
    const float* __restrict__ X, u8* __restrict__ Xq4T)
{
    const int idx = blockIdx.x * 256 + threadIdx.x;   // uint2 units
    const int q  = idx & 63;
    const int h  = idx >> 6;
    const int kt = h % NKT;
    const int u  = h / NKT;
    const int bg = u & 255;
    const int t  = u >> 8;
    const int r  = q >> 2;
    const int ls = q & 3;
    const long m  = (long)t * B_SZ + bg * 16 + r;
    const int k0 = kt * 64 + ls * 16;
    uint2 o = make_uint2(0u, 0u);
    if (k0 + 16 <= N_IN) {
        const uint4* src = reinterpret_cast<const uint4*>(X + m * N_IN + k0);
        const uint4 f0 = src[0], f1 = src[1], f2 = src[2], f3 = src[3];
        auto nib = [](uint4 a, uint4 b) -> u32 {
            return (a.x ? 1u : 0u)        | ((a.y ? 1u : 0u) << 4)  |
                   ((a.z ? 1u : 0u) << 8) | ((a.w ? 1u : 0u) << 12) |
                   ((b.x ? 1u : 0u) << 16)| ((b.y ? 1u : 0u) << 20) |
                   ((b.z ? 1u : 0u) << 24)| ((b.w ? 1u : 0u) << 28);
        };
        o.x = nib(f0, f1);
        o.y = nib(f2, f3);
    }
    reinterpret_cast<uint2*>(Xq4T)[idx] = o;
}

// ---------------- conv_w3: W1 -> 3 i8 planes (power-of-2 scales) -----------
__global__ __launch_bounds__(256) void conv_w3(
    const float* __restrict__ W1, char* __restrict__ Wq)
{
    const int idx = blockIdx.x * 256 + threadIdx.x;   // over 256*832
    if (idx >= N_HID * KP8) return;
    const int n = idx / KP8, k = idx % KP8;
    const float w = (k < N_IN) ? W1[n * N_IN + k] : 0.0f;
    const float a = rintf(w * 2048.0f);                       // s1 = 2^-11
    const float r1 = fmaf(a, -4.8828125e-4f, w);
    const float b = rintf(r1 * 262144.0f);                    // s2 = 2^-18
    const float r2 = fmaf(b, -3.814697265625e-6f, r1);
    const float c = rintf(r2 * 33554432.0f);                  // s3 = 2^-25
    Wq[idx]              = (char)(int)a;
    Wq[WPLANE + idx]     = (char)(int)b;
    Wq[2 * WPLANE + idx] = (char)(int)c;
}

// ---------------- gemm1 + lif1 fused: 16x16xT4 waves -----------------------
__global__ __launch_bounds__(256, 3) void gemm1_lif1(
    const u8* __restrict__ Xq4T,
    const u8* __restrict__ Wq,
    const float* __restrict__ b1,
    u8* __restrict__ Z1S)
{
    __shared__ u8 Bq[3 * WPL];          // 40,704 B

    const int tid  = threadIdx.x;
    const int lane = tid & 63;
    const int w    = tid >> 6;          // wave 0..3: m-rows w*16..+16
    const int bid  = blockIdx.x;        // 1024 blocks
    const int l    = (bid & 7) * 128 + (bid >> 3);  // XCD-grouped
    const int bt   = l >> 4;            // b-tile of 64 rows (0..63)
    const int nt   = l & 15;            // n-tile of 16 cols (0..15)
    const int n0   = nt * 16;
    const int ls   = lane >> 4;         // k-slot 0..3
    const int lr   = lane & 15;

    // ---- W -> LDS via regs (r9-verified staging; 848 stride) ----
    #pragma unroll
    for (int it = 0; it < 10; ++it) {
        const int u = it * 256 + tid;                 // 3*16*52 = 2496 units
        if (u < 2496) {
            const int plane = u / 832;
            const int rem   = u - plane * 832;
            const int row   = rem / 52;               // col within slice
            const int sp    = rem - row * 52;         // 16B slot
            const uint4 v = *reinterpret_cast<const uint4*>(
                Wq + (size_t)plane * WPLANE + (size_t)(n0 + row) * KP8 + sp * 16);
            *reinterpret_cast<uint4*>(&Bq[plane * WPL + row * WROW + sp * 16]) = v;
        }
    }
    __syncthreads();                    // the only barrier

    const float bb = b1[n0 + lr];
    float vS[4], cS[4];                 // LIF state: m = bg*16 + ls*4+q
    #pragma unroll
    for (int k = 0; k < 4; ++k) { vS[k] = 0.0f; cS[k] = 0.0f; }

    int bO[3];
    #pragma unroll
    for (int p = 0; p < 3; ++p) bO[p] = p * WPL + lr * WROW + (ls << 4);

    const int bg = bt * 4 + w;          // this wave's 16-row group (0..255)
    const u8* aP = Xq4T + (size_t)bg * (NKT * 512) + lr * 32 + ls * 8;

    const float s1 = 4.8828125e-4f;          // 2^-11
    const float s2 = 3.814697265625e-6f;     // 2^-18
    const float s3 = 2.9802322387695312e-8f; // 2^-25

    for (int g = 0; g < 4; ++g) {       // 4 groups x 4 timesteps
        i32x4 acc[4][3];                // [tt][plane] = 48 regs
        #pragma unroll
        for (int tt = 0; tt < 4; ++tt)
            #pragma unroll
            for (int p = 0; p < 3; ++p)
                acc[tt][p] = (i32x4){0, 0, 0, 0};

        uint2 ar[3][4];                 // rolling A [ring][tt], 2-step lead
        #pragma unroll
        for (int pk = 0; pk < 2; ++pk)
            #pragma unroll
            for (int tt = 0; tt < 4; ++tt)
                ar[pk][tt] = *reinterpret_cast<const uint2*>(
                    aP + tt * TSH + pk * 512);

        #pragma unroll
        for (int kt = 0; kt < NKT; ++kt) {
            if (kt + 2 < NKT) {         // prefetch 2 k-steps ahead (static ring)
                #pragma unroll
                for (int tt = 0; tt < 4; ++tt)
                    ar[(kt + 2) % 3][tt] = *reinterpret_cast<const uint2*>(
                        aP + tt * TSH + (kt + 2) * 512);
            }
            uint4 bf[3];
            #pragma unroll
            for (int p = 0; p < 3; ++p)
                bf[p] = *reinterpret_cast<const uint4*>(&Bq[bO[p] + kt * 64]);

            __builtin_amdgcn_s_setprio(1);
            #pragma unroll
            for (int tt = 0; tt < 4; ++tt) {
                const uint4 af = unp(ar[kt % 3][tt]);
                #pragma unroll
                for (int p = 0; p < 3; ++p)
                    acc[tt][p] = __builtin_amdgcn_mfma_i32_16x16x64_i8(
                        __builtin_bit_cast(i32x4, af),
                        __builtin_bit_cast(i32x4, bf[p]),
                        acc[tt][p], 0, 0, 0);
            }
            __builtin_amdgcn_s_setprio(0);
        }
        aP += 4 * TSH;

        // LIF + store: lane-contiguous tile [m>>2][n][m&3]; lane L -> byte L*4
        #pragma unroll
        for (int tt = 0; tt < 4; ++tt) {
            const int t = 4 * g + tt;
            u32 zw = 0;
            #pragma unroll
            for (int q = 0; q < 4; ++q) {
                const float c1 = fmaf(s1, (float)acc[tt][0][q],
                                 fmaf(s2, (float)acc[tt][1][q],
                                 fmaf(s3, (float)acc[tt][2][q], bb)));
                const float vd = vS[q] + 0.1f * ((0.0f - vS[q]) + cS[q]);
                const float id = cS[q] - 0.2f * cS[q];
                const bool  sp = vd > 1.0f;
                zw |= (sp ? 1u : 0u) << (8 * q);
                vS[q] = sp ? 0.0f : vd;
                cS[q] = id + c1;
            }
            u32* dst = reinterpret_cast<u32*>(
                Z1S + ((size_t)(t * 16 + nt) * 256 + bg) * 256
                    + lane * 4);        // ls*64 + lr*4: adjacent lanes adjacent
            *dst = zw;
        }
    }
}

// ---------------- GEMM2: C2T[o][m] from Z1S tiles ([m>>2][n][m&3] order) ---
__global__ __launch_bounds__(256) void gemm2_f32(
    const u8* __restrict__ Z1S, const float* __restrict__ W2,
    const float* __restrict__ b2, float* __restrict__ C2T)
{
    __shared__ float ws[N_OUT * N_HID];   // 10 KB
    const int tid = threadIdx.x;
    const int t   = blockIdx.x >> 4;
    const int b   = (blockIdx.x & 15) * 256 + tid;

    for (int i = tid; i < N_OUT * N_HID; i += 256) ws[i] = W2[i];
    __syncthreads();

    float acc[N_OUT];
    #pragma unroll
    for (int o = 0; o < N_OUT; ++o) acc[o] = b2[o];

    const int msl = (b & 15) >> 2;      // m-slot within tile
    const int mq  = b & 3;              // m byte within slot
    const u8* zb = Z1S + (size_t)(t * 16) * 65536
                 + (size_t)(b >> 4) * 256 + msl * 64 + mq;
    for (int n0 = 0; n0 < N_HID; n0 += 8) {        // nt fixed per group
        const int nt = n0 >> 4, r0 = n0 & 15;
        const u8* zr = zb + (size_t)nt * 65536 + r0 * 4;
        float zf[8];
        #pragma unroll
        for (int j = 0; j < 8; ++j)
            zf[j] = (float)zr[j * 4];
        #pragma unroll
        for (int o = 0; o < N_OUT; ++o) {          // same expr as r13 (passed)
            acc[o] += zf[0] * ws[o * N_HID + n0 + 0] + zf[1] * ws[o * N_HID + n0 + 1]
                    + zf[2] * ws[o * N_HID + n0 + 2] + zf[3] * ws[o * N_HID + n0 + 3];
            acc[o] += zf[4] * ws[o * N_HID + n0 + 4] + zf[5] * ws[o * N_HID + n0 + 5]
                    + zf[6] * ws[o * N_HID + n0 + 6] + zf[7] * ws[o * N_HID + n0 + 7];
        }
    }
    #pragma unroll
    for (int o = 0; o < N_OUT; ++o)
        C2T[(size_t)o * M_TOT + t * B_SZ + b] = acc[o];
}

// ---------------- LIF2: thread = (o,b); reads C2T [r13-verified] -----------
__global__ __launch_bounds__(256) void lif2_kernel(
    const float* __restrict__ C2T, float* __restrict__ out)
{
    const int g = blockIdx.x * 256 + threadIdx.x;   // < 40960
    const int o = g >> 12;              // 0..9
    const int b = g & (B_SZ - 1);
    float v = 0.0f, cur = 0.0f, s = 0.0f;
    #pragma unroll
    for (int t = 0; t < T_STEPS; ++t) {
        const float c = C2T[(size_t)o * M_TOT + t * B_SZ + b];
        const float vd = v + 0.1f * ((0.0f - v) + cur);
        const float id = cur - 0.2f * cur;
        const bool  sp = vd > 1.0f;
        s += sp ? 1.0f : 0.0f;
        v = sp ? 0.0f : vd;
        cur = id + c;
    }
    out[b * N_OUT + o] = s;
}

extern "C" void kernel_launch(void* const* d_in, const int* in_sizes, int n_in,
                              void* d_out, int out_size, void* d_ws, size_t ws_size,
                              hipStream_t stream)
{
    const float* X  = (const float*)d_in[0];
    const float* W1 = (const float*)d_in[1];
    const float* b1 = (const float*)d_in[2];
    const float* W2 = (const float*)d_in[3];
    const float* b2 = (const float*)d_in[4];
    float* out = (float*)d_out;

    // ws: [Wq 0.64MB | pad->1MB][Xq4T 27.3MB][Z1S 16.8MB][C2T 2.6MB] ~48MB
    char* Wq = (char*)d_ws;
    u8*   Xq4T = (u8*)d_ws + (1 << 20);
    u8*   Z1S = Xq4T + (size_t)M_TOT * (KP8 / 2);
    float* C2T = (float*)(Z1S + (size_t)M_TOT * N_HID);

    conv_x<<<(M_TOT * 52) / 256, 256, 0, stream>>>(X, Xq4T);

    conv_w3<<<(N_HID * KP8 + 255) / 256, 256, 0, stream>>>(W1, Wq);

    gemm1_lif1<<<1024, 256, 0, stream>>>(Xq4T, (const u8*)Wq, b1, Z1S);

    gemm2_f32<<<256, 256, 0, stream>>>(Z1S, W2, b2, C2T);

    lif2_kernel<<<(B_SZ * N_OUT) / 256, 256, 0, stream>>>(C2T, out);
}